// Round 11
// baseline (412.446 us; speedup 1.0000x reference)
//
#include <hip/hip_runtime.h>

// one_layer_gcn: GCNConv(512 -> 1) + ReLU
// out[v] = relu( dinv[v] * ( sum_{(s->v)} h[s]*dinv[s] + h[v]*dinv[v] ) + b )
// h = x @ W, dinv[v] = rsqrt(deg_in_with_selfloop[v])
//
// ROUND-11 = MEASUREMENT ROUND #2. Round-10 pipeline verbatim (best, 245.8us)
// with the idempotent pair {init_cursor; place} run 4x.
//   place_t ~= (T11 - 245.8)/3 - (init+gap ~9us)
// init resets cursors; place re-deposits the identical edge multiset into the
// identical bucket extents (consumers are order-invariant), so the final
// state and output are bit-identical to round 10.

#define GCN_D 512
#define NPB 16384         // nodes per bucket
#define NPB_SHIFT 14
#define MAXNBK 16         // bucket-count bound (N <= 262144)
#define SPLIT 16          // sub-blocks per bucket in deg/gather p1
#define CHUNK 8192        // edges per place block
#define PT 512            // place threads
#define CPAD 16           // cursor padding (ints)

// ---------------- init per-bucket cursors to b*CAP ----------------
__global__ void init_cursor_kernel(int* __restrict__ cursor, int NBK, int CAP) {
    int i = threadIdx.x;
    if (i < NBK) cursor[i * CPAD] = i * CAP;
}

// ---------------- place: multisplit into 13 coarse buckets ----------------
// record: (src << 14) | (dst & 16383)   -- needs src < 2^18
__global__ __launch_bounds__(PT) void place_kernel(const int* __restrict__ src,
                                                   const int* __restrict__ dst,
                                                   int* __restrict__ cursor,
                                                   unsigned int* __restrict__ packed,
                                                   int E, int NBK, int CAP) {
    __shared__ unsigned int staging[CHUNK];    // 32 KB
    __shared__ int hist[MAXNBK];
    __shared__ int lstart[MAXNBK];
    __shared__ int lcur[MAXNBK];
    __shared__ int gbase[MAXNBK];

    const int tid = threadIdx.x;
    const int e0 = blockIdx.x * CHUNK;
    const int rem = min(CHUNK, E - e0);        // E,CHUNK div by 4 => rem%4==0
    const int r4 = rem >> 2;

    const int4* d4p = reinterpret_cast<const int4*>(dst + e0);
    const int4* s4p = reinterpret_cast<const int4*>(src + e0);

    if (tid < MAXNBK) hist[tid] = 0;
    __syncthreads();

    int4 dreg[4];
    #pragma unroll
    for (int k = 0; k < 4; ++k) {
        int i4 = tid + k * PT;
        if (i4 < r4) {
            dreg[k] = d4p[i4];
            atomicAdd(&hist[dreg[k].x >> NPB_SHIFT], 1);
            atomicAdd(&hist[dreg[k].y >> NPB_SHIFT], 1);
            atomicAdd(&hist[dreg[k].z >> NPB_SHIFT], 1);
            atomicAdd(&hist[dreg[k].w >> NPB_SHIFT], 1);
        }
    }
    __syncthreads();

    if (tid == 0) {                             // 13-entry serial scan
        int run = 0;
        for (int b = 0; b < NBK; ++b) { lstart[b] = run; lcur[b] = run; run += hist[b]; }
    }
    __syncthreads();
    if (tid < NBK) {
        int c = hist[tid];
        gbase[tid] = c ? atomicAdd(&cursor[tid * CPAD], c) : 0;
    }
    __syncthreads();

    #pragma unroll
    for (int k = 0; k < 4; ++k) {
        int i4 = tid + k * PT;
        if (i4 < r4) {
            int4 s4 = s4p[i4];
            int4 d = dreg[k];
            int b, pos;
            b = d.x >> NPB_SHIFT; pos = atomicAdd(&lcur[b], 1);
            staging[pos] = ((unsigned)s4.x << NPB_SHIFT) | (unsigned)(d.x & (NPB - 1));
            b = d.y >> NPB_SHIFT; pos = atomicAdd(&lcur[b], 1);
            staging[pos] = ((unsigned)s4.y << NPB_SHIFT) | (unsigned)(d.y & (NPB - 1));
            b = d.z >> NPB_SHIFT; pos = atomicAdd(&lcur[b], 1);
            staging[pos] = ((unsigned)s4.z << NPB_SHIFT) | (unsigned)(d.z & (NPB - 1));
            b = d.w >> NPB_SHIFT; pos = atomicAdd(&lcur[b], 1);
            staging[pos] = ((unsigned)s4.w << NPB_SHIFT) | (unsigned)(d.w & (NPB - 1));
        }
    }
    __syncthreads();

    // per-bucket contiguous copy-out: block-wide streaming stores
    for (int b = 0; b < NBK; ++b) {
        int cnt = hist[b];
        if (!cnt) continue;
        int ls = lstart[b];
        int gb = gbase[b];
        int capend = (b + 1) * CAP;
        for (int p = tid; p < cnt; p += PT) {
            int gp = gb + p;
            if (gp < capend)                    // clamp (never hits on-bench)
                packed[gp] = staging[ls + p];
        }
    }
}

// ---------------- deg pass 1: per-(bucket,split) 64KB-LDS count -> partials ----
__global__ __launch_bounds__(1024) void deg_p1_kernel(const unsigned int* __restrict__ packed,
                                                      const int* __restrict__ cursor,
                                                      int* __restrict__ dpart,
                                                      int NBK, int CAP) {
    int b = blockIdx.x / SPLIT;
    int part = blockIdx.x % SPLIT;
    __shared__ int acc[NPB];                   // 64 KB
    for (int i = threadIdx.x; i < NPB; i += blockDim.x) acc[i] = 0;
    __syncthreads();
    int s0 = b * CAP;
    int s1 = min(cursor[b * CPAD], (b + 1) * CAP);
    int cnt = s1 - s0;
    int n4 = cnt >> 2;
    const uint4* p4 = reinterpret_cast<const uint4*>(packed + s0);   // CAP%4==0
    for (int i = threadIdx.x + part * blockDim.x; i < n4; i += SPLIT * blockDim.x) {
        uint4 p = p4[i];
        atomicAdd(&acc[p.x & (NPB - 1)], 1);
        atomicAdd(&acc[p.y & (NPB - 1)], 1);
        atomicAdd(&acc[p.z & (NPB - 1)], 1);
        atomicAdd(&acc[p.w & (NPB - 1)], 1);
    }
    if (part == 0 && threadIdx.x < (cnt & 3))
        atomicAdd(&acc[packed[s0 + (n4 << 2) + threadIdx.x] & (NPB - 1)], 1);
    __syncthreads();
    int* dp = dpart + (size_t)(b * SPLIT + part) * NPB;
    for (int i = threadIdx.x; i < NPB; i += blockDim.x) dp[i] = acc[i];   // streaming
}

// ---------------- deg reduce: dinv[v] = rsqrt(sum16 + 1) ----------------
__global__ void deg_red_kernel(const int* __restrict__ dpart, float* __restrict__ dinv,
                               int n) {
    int v = blockIdx.x * blockDim.x + threadIdx.x;
    if (v < n) {
        int b = v >> NPB_SHIFT;
        int idx = v & (NPB - 1);
        const int* dp = dpart + (size_t)(b * SPLIT) * NPB + idx;
        int s = 0;
        #pragma unroll
        for (int k = 0; k < SPLIT; ++k) s += dp[(size_t)k * NPB];
        dinv[v] = rsqrtf((float)(s + 1));
    }
}

// ---------------- GEMV: hprime[row] = dot(x[row,:], W) * dinv[row] ------------
__global__ void gemv_kernel(const float* __restrict__ x, const float* __restrict__ W,
                            const float* __restrict__ dinv, float* __restrict__ hprime,
                            int n) {
    int wave = threadIdx.x >> 6;
    int lane = threadIdx.x & 63;
    int row = blockIdx.x * 4 + wave;
    if (row >= n) return;

    const float4* xr = reinterpret_cast<const float4*>(x + (size_t)row * GCN_D);
    const float4* Wv = reinterpret_cast<const float4*>(W);

    float4 a0 = xr[lane];
    float4 w0 = Wv[lane];
    float4 a1 = xr[lane + 64];
    float4 w1 = Wv[lane + 64];

    float dot = a0.x * w0.x + a0.y * w0.y + a0.z * w0.z + a0.w * w0.w
              + a1.x * w1.x + a1.y * w1.y + a1.z * w1.z + a1.w * w1.w;

    #pragma unroll
    for (int off = 32; off >= 1; off >>= 1)
        dot += __shfl_down(dot, off, 64);

    if (lane == 0) hprime[row] = dot * dinv[row];
}

// ---------------- gather pass 1: per-(bucket,split) 64KB-LDS float accum ------
__global__ __launch_bounds__(1024) void gather_p1_kernel(const unsigned int* __restrict__ packed,
                                                         const int* __restrict__ cursor,
                                                         const float* __restrict__ hprime,
                                                         float* __restrict__ gpart,
                                                         int NBK, int CAP) {
    int b = blockIdx.x / SPLIT;
    int part = blockIdx.x % SPLIT;
    __shared__ float acc[NPB];                 // 64 KB
    for (int i = threadIdx.x; i < NPB; i += blockDim.x) acc[i] = 0.f;
    __syncthreads();
    int s0 = b * CAP;
    int s1 = min(cursor[b * CPAD], (b + 1) * CAP);
    int cnt = s1 - s0;
    int n4 = cnt >> 2;
    const uint4* p4 = reinterpret_cast<const uint4*>(packed + s0);
    for (int i = threadIdx.x + part * blockDim.x; i < n4; i += SPLIT * blockDim.x) {
        uint4 p = p4[i];
        atomicAdd(&acc[p.x & (NPB - 1)], hprime[p.x >> NPB_SHIFT]);
        atomicAdd(&acc[p.y & (NPB - 1)], hprime[p.y >> NPB_SHIFT]);
        atomicAdd(&acc[p.z & (NPB - 1)], hprime[p.z >> NPB_SHIFT]);
        atomicAdd(&acc[p.w & (NPB - 1)], hprime[p.w >> NPB_SHIFT]);
    }
    if (part == 0 && threadIdx.x < (cnt & 3)) {
        unsigned p = packed[s0 + (n4 << 2) + threadIdx.x];
        atomicAdd(&acc[p & (NPB - 1)], hprime[p >> NPB_SHIFT]);
    }
    __syncthreads();
    float* gp = gpart + (size_t)(b * SPLIT + part) * NPB;
    for (int i = threadIdx.x; i < NPB; i += blockDim.x) gp[i] = acc[i];   // streaming
}

// ---------------- gather reduce + finalize ----------------
__global__ void gather_red_kernel(const float* __restrict__ gpart,
                                  const float* __restrict__ hprime,
                                  const float* __restrict__ dinv,
                                  const float* __restrict__ bias,
                                  float* __restrict__ out, int n) {
    int v = blockIdx.x * blockDim.x + threadIdx.x;
    if (v < n) {
        int b = v >> NPB_SHIFT;
        int idx = v & (NPB - 1);
        const float* gp = gpart + (size_t)(b * SPLIT) * NPB + idx;
        float s = 0.f;
        #pragma unroll
        for (int k = 0; k < SPLIT; ++k) s += gp[(size_t)k * NPB];
        float val = dinv[v] * (s + hprime[v]) + bias[0];
        out[v] = val > 0.f ? val : 0.f;
    }
}

// ---------------- fallback path (global atomics; tiny ws only) ----------------
__global__ void deg_atomic_kernel(const int* __restrict__ dst, int* __restrict__ deg, int e4) {
    int i = blockIdx.x * blockDim.x + threadIdx.x;
    if (i < e4) {
        int4 d = reinterpret_cast<const int4*>(dst)[i];
        atomicAdd(&deg[d.x], 1);
        atomicAdd(&deg[d.y], 1);
        atomicAdd(&deg[d.z], 1);
        atomicAdd(&deg[d.w], 1);
    }
}
__global__ void gemv_scaled_fb_kernel(const float* __restrict__ x, const float* __restrict__ W,
                                      const int* __restrict__ deg, float* __restrict__ hprime,
                                      int n) {
    int wave = threadIdx.x >> 6;
    int lane = threadIdx.x & 63;
    int row = blockIdx.x * 4 + wave;
    if (row >= n) return;
    const float4* xr = reinterpret_cast<const float4*>(x + (size_t)row * GCN_D);
    const float4* Wv = reinterpret_cast<const float4*>(W);
    float4 a0 = xr[lane], w0 = Wv[lane];
    float4 a1 = xr[lane + 64], w1 = Wv[lane + 64];
    float dot = a0.x * w0.x + a0.y * w0.y + a0.z * w0.z + a0.w * w0.w
              + a1.x * w1.x + a1.y * w1.y + a1.z * w1.z + a1.w * w1.w;
    #pragma unroll
    for (int off = 32; off >= 1; off >>= 1) dot += __shfl_down(dot, off, 64);
    if (lane == 0) hprime[row] = dot * rsqrtf((float)(deg[row] + 1));
}
__global__ void scatter_kernel(const int* __restrict__ src, const int* __restrict__ dst,
                               const float* __restrict__ hprime, float* __restrict__ acc,
                               int e4) {
    int i = blockIdx.x * blockDim.x + threadIdx.x;
    if (i < e4) {
        int4 s = reinterpret_cast<const int4*>(src)[i];
        int4 d = reinterpret_cast<const int4*>(dst)[i];
        atomicAdd(&acc[d.x], hprime[s.x]);
        atomicAdd(&acc[d.y], hprime[s.y]);
        atomicAdd(&acc[d.z], hprime[s.z]);
        atomicAdd(&acc[d.w], hprime[s.w]);
    }
}
__global__ void final_fb_kernel(const float* __restrict__ hprime, const float* __restrict__ accg,
                                const int* __restrict__ deg, const float* __restrict__ bptr,
                                float* __restrict__ out, int n) {
    int i = blockIdx.x * blockDim.x + threadIdx.x;
    if (i < n) {
        float dinv = rsqrtf((float)(deg[i] + 1));
        float v = dinv * (accg[i] + hprime[i]) + bptr[0];
        out[i] = v > 0.0f ? v : 0.0f;
    }
}

extern "C" void kernel_launch(void* const* d_in, const int* in_sizes, int n_in,
                              void* d_out, int out_size, void* d_ws, size_t ws_size,
                              hipStream_t stream) {
    const float* x    = (const float*)d_in[0];
    const int*   ei   = (const int*)d_in[1];   // [2, E]: row0 = src, row1 = dst
    const float* W    = (const float*)d_in[2];
    const float* bias = (const float*)d_in[3];
    float* out = (float*)d_out;

    const int n = in_sizes[0] / GCN_D;         // 200000
    const int E = in_sizes[1] / 2;             // 12800000
    const int e4 = E / 4;

    const int* src = ei;
    const int* dst = ei + E;

    const int NBK = (n + NPB - 1) >> NPB_SHIFT;   // 13

    // bucket capacity: ~1.125x expected max-bucket load (sigma ~1K, huge margin)
    long long lam = ((long long)E * NPB + n - 1) / (n > 0 ? n : 1);
    if (lam < 16) lam = 16;
    long long capll = lam + lam / 8 + 4096;
    int CAP = (int)((capll + 3) & ~3LL);

    // ws layout: dinv[n] | hprime[n] | cursor | dpart[NBK*16*NPB] | gpart[same] | packed[NBK*CAP]
    auto align64 = [](size_t v) { return (v + 63) & ~(size_t)63; };
    size_t off_dinv   = 0;
    size_t off_hprime = align64(off_dinv   + (size_t)n * 4);
    size_t off_cursor = align64(off_hprime + (size_t)n * 4);
    size_t off_dpart  = align64(off_cursor + (size_t)MAXNBK * CPAD * 4);
    size_t off_gpart  = align64(off_dpart  + (size_t)NBK * SPLIT * NPB * 4);
    size_t off_packed = align64(off_gpart  + (size_t)NBK * SPLIT * NPB * 4);
    size_t needed     = off_packed + (size_t)NBK * CAP * 4;

    char* ws = (char*)d_ws;
    float* dinv   = (float*)(ws + off_dinv);
    float* hprime = (float*)(ws + off_hprime);

    if (NBK <= MAXNBK && n <= (1 << 18) && ws_size >= needed) {
        int* cursor = (int*)(ws + off_cursor);
        int* dpart  = (int*)(ws + off_dpart);
        float* gpart = (float*)(ws + off_gpart);
        unsigned int* packed = (unsigned int*)(ws + off_packed);

        const int PBLK = (E + CHUNK - 1) / CHUNK;

        // MEASUREMENT: idempotent pair {init_cursor; place} x4.
        // place_t = (T11 - T10)/3 - (init+gaps). Final state identical to 1x.
        for (int rep = 0; rep < 4; ++rep) {
            init_cursor_kernel<<<1, 64, 0, stream>>>(cursor, NBK, CAP);
            place_kernel<<<PBLK, PT, 0, stream>>>(src, dst, cursor, packed, E, NBK, CAP);
        }
        deg_p1_kernel<<<NBK * SPLIT, 1024, 0, stream>>>(packed, cursor, dpart, NBK, CAP);
        deg_red_kernel<<<(n + 255) / 256, 256, 0, stream>>>(dpart, dinv, n);
        gemv_kernel<<<(n + 3) / 4, 256, 0, stream>>>(x, W, dinv, hprime, n);
        gather_p1_kernel<<<NBK * SPLIT, 1024, 0, stream>>>(packed, cursor, hprime, gpart, NBK, CAP);
        gather_red_kernel<<<(n + 255) / 256, 256, 0, stream>>>(gpart, hprime, dinv, bias, out, n);
    } else {
        // fallback: atomic path (slow but correct, tiny ws)
        int*   deg   = (int*)(ws + off_dinv);
        float* accfb = (float*)(ws + off_cursor);
        hipMemsetAsync(ws, 0, off_cursor + (size_t)n * 4, stream);
        deg_atomic_kernel<<<(e4 + 255) / 256, 256, 0, stream>>>(dst, deg, e4);
        gemv_scaled_fb_kernel<<<(n + 3) / 4, 256, 0, stream>>>(x, W, deg, hprime, n);
        scatter_kernel<<<(e4 + 255) / 256, 256, 0, stream>>>(src, dst, hprime, accfb, e4);
        final_fb_kernel<<<(n + 255) / 256, 256, 0, stream>>>(hprime, accfb, deg, bias, out, n);
    }
}

// Round 12
// 242.669 us; speedup vs baseline: 1.6996x; 1.6996x over previous
//
#include <hip/hip_runtime.h>

// one_layer_gcn: GCNConv(512 -> 1) + ReLU
// out[v] = relu( dinv[v] * ( sum_{(s->v)} h[s]*dinv[s] + h[v]*dinv[v] ) + b )
// h = x @ W, dinv[v] = rsqrt(deg_in_with_selfloop[v])
//
// Round-12: measurements pinned place=~51us, gemv=62us(BW floor), and
// deg_p1+gather_p1 = ~105us. Cause: 208 blocks w/ 64KB LDS = sub-1-block/CU
// grid; each block reads ~1MB through ONE CU (~25GB/s per-CU) -> per-CU-BW
// bound. Fix: NPB=8192 (NBK=25, 32KB LDS), 512-thr blocks, SPLIT=32 -> 800
// blocks, 4 blocks/CU -> reads spread across all CUs. Partials 26MB/pass.

#define GCN_D 512
#define NPB 8192          // nodes per bucket
#define NPB_SHIFT 13
#define MAXNBK 32         // bucket-count bound (N <= 262144)
#define SPLIT 32          // sub-blocks per bucket in deg/gather p1
#define CHUNK 8192        // edges per place block
#define PT 512            // place threads
#define P1T 512           // p1 threads
#define CPAD 16           // cursor padding (ints)

// ---------------- init per-bucket cursors to b*CAP ----------------
__global__ void init_cursor_kernel(int* __restrict__ cursor, int NBK, int CAP) {
    int i = threadIdx.x;
    if (i < NBK) cursor[i * CPAD] = i * CAP;
}

// ---------------- place: multisplit into 25 coarse buckets ----------------
// record: (src << 13) | (dst & 8191)   -- src < 2^18, fits u32
__global__ __launch_bounds__(PT) void place_kernel(const int* __restrict__ src,
                                                   const int* __restrict__ dst,
                                                   int* __restrict__ cursor,
                                                   unsigned int* __restrict__ packed,
                                                   int E, int NBK, int CAP) {
    __shared__ unsigned int staging[CHUNK];    // 32 KB
    __shared__ int hist[MAXNBK];
    __shared__ int lstart[MAXNBK];
    __shared__ int lcur[MAXNBK];
    __shared__ int gbase[MAXNBK];

    const int tid = threadIdx.x;
    const int e0 = blockIdx.x * CHUNK;
    const int rem = min(CHUNK, E - e0);        // E,CHUNK div by 4 => rem%4==0
    const int r4 = rem >> 2;

    const int4* d4p = reinterpret_cast<const int4*>(dst + e0);
    const int4* s4p = reinterpret_cast<const int4*>(src + e0);

    if (tid < MAXNBK) hist[tid] = 0;
    __syncthreads();

    int4 dreg[4];
    #pragma unroll
    for (int k = 0; k < 4; ++k) {
        int i4 = tid + k * PT;
        if (i4 < r4) {
            dreg[k] = d4p[i4];
            atomicAdd(&hist[dreg[k].x >> NPB_SHIFT], 1);
            atomicAdd(&hist[dreg[k].y >> NPB_SHIFT], 1);
            atomicAdd(&hist[dreg[k].z >> NPB_SHIFT], 1);
            atomicAdd(&hist[dreg[k].w >> NPB_SHIFT], 1);
        }
    }
    __syncthreads();

    if (tid == 0) {                             // 25-entry serial scan
        int run = 0;
        for (int b = 0; b < NBK; ++b) { lstart[b] = run; lcur[b] = run; run += hist[b]; }
    }
    __syncthreads();
    if (tid < NBK) {
        int c = hist[tid];
        gbase[tid] = c ? atomicAdd(&cursor[tid * CPAD], c) : 0;
    }
    __syncthreads();

    #pragma unroll
    for (int k = 0; k < 4; ++k) {
        int i4 = tid + k * PT;
        if (i4 < r4) {
            int4 s4 = s4p[i4];
            int4 d = dreg[k];
            int b, pos;
            b = d.x >> NPB_SHIFT; pos = atomicAdd(&lcur[b], 1);
            staging[pos] = ((unsigned)s4.x << NPB_SHIFT) | (unsigned)(d.x & (NPB - 1));
            b = d.y >> NPB_SHIFT; pos = atomicAdd(&lcur[b], 1);
            staging[pos] = ((unsigned)s4.y << NPB_SHIFT) | (unsigned)(d.y & (NPB - 1));
            b = d.z >> NPB_SHIFT; pos = atomicAdd(&lcur[b], 1);
            staging[pos] = ((unsigned)s4.z << NPB_SHIFT) | (unsigned)(d.z & (NPB - 1));
            b = d.w >> NPB_SHIFT; pos = atomicAdd(&lcur[b], 1);
            staging[pos] = ((unsigned)s4.w << NPB_SHIFT) | (unsigned)(d.w & (NPB - 1));
        }
    }
    __syncthreads();

    // per-bucket contiguous copy-out: block-wide streaming stores
    for (int b = 0; b < NBK; ++b) {
        int cnt = hist[b];
        if (!cnt) continue;
        int ls = lstart[b];
        int gb = gbase[b];
        int capend = (b + 1) * CAP;
        for (int p = tid; p < cnt; p += PT) {
            int gp = gb + p;
            if (gp < capend)                    // clamp (never hits on-bench)
                packed[gp] = staging[ls + p];
        }
    }
}

// ---------------- deg pass 1: per-(bucket,split) 32KB-LDS count -> partials ----
__global__ __launch_bounds__(P1T) void deg_p1_kernel(const unsigned int* __restrict__ packed,
                                                     const int* __restrict__ cursor,
                                                     int* __restrict__ dpart,
                                                     int NBK, int CAP) {
    int b = blockIdx.x / SPLIT;
    int part = blockIdx.x % SPLIT;
    __shared__ int acc[NPB];                   // 32 KB
    for (int i = threadIdx.x; i < NPB; i += P1T) acc[i] = 0;
    __syncthreads();
    int s0 = b * CAP;
    int s1 = min(cursor[b * CPAD], (b + 1) * CAP);
    int cnt = s1 - s0;
    int n4 = cnt >> 2;
    const uint4* p4 = reinterpret_cast<const uint4*>(packed + s0);   // CAP%4==0
    for (int i = threadIdx.x + part * P1T; i < n4; i += SPLIT * P1T) {
        uint4 p = p4[i];
        atomicAdd(&acc[p.x & (NPB - 1)], 1);
        atomicAdd(&acc[p.y & (NPB - 1)], 1);
        atomicAdd(&acc[p.z & (NPB - 1)], 1);
        atomicAdd(&acc[p.w & (NPB - 1)], 1);
    }
    if (part == 0 && threadIdx.x < (cnt & 3))
        atomicAdd(&acc[packed[s0 + (n4 << 2) + threadIdx.x] & (NPB - 1)], 1);
    __syncthreads();
    int* dp = dpart + (size_t)(b * SPLIT + part) * NPB;
    for (int i = threadIdx.x; i < NPB; i += P1T) dp[i] = acc[i];   // streaming
}

// ---------------- deg reduce: dinv[v] = rsqrt(sum32 + 1) ----------------
__global__ void deg_red_kernel(const int* __restrict__ dpart, float* __restrict__ dinv,
                               int n) {
    int v = blockIdx.x * blockDim.x + threadIdx.x;
    if (v < n) {
        int b = v >> NPB_SHIFT;
        int idx = v & (NPB - 1);
        const int* dp = dpart + (size_t)(b * SPLIT) * NPB + idx;
        int s = 0;
        #pragma unroll
        for (int k = 0; k < SPLIT; ++k) s += dp[(size_t)k * NPB];
        dinv[v] = rsqrtf((float)(s + 1));
    }
}

// ---------------- GEMV: hprime[row] = dot(x[row,:], W) * dinv[row] ------------
__global__ void gemv_kernel(const float* __restrict__ x, const float* __restrict__ W,
                            const float* __restrict__ dinv, float* __restrict__ hprime,
                            int n) {
    int wave = threadIdx.x >> 6;
    int lane = threadIdx.x & 63;
    int row = blockIdx.x * 4 + wave;
    if (row >= n) return;

    const float4* xr = reinterpret_cast<const float4*>(x + (size_t)row * GCN_D);
    const float4* Wv = reinterpret_cast<const float4*>(W);

    float4 a0 = xr[lane];
    float4 w0 = Wv[lane];
    float4 a1 = xr[lane + 64];
    float4 w1 = Wv[lane + 64];

    float dot = a0.x * w0.x + a0.y * w0.y + a0.z * w0.z + a0.w * w0.w
              + a1.x * w1.x + a1.y * w1.y + a1.z * w1.z + a1.w * w1.w;

    #pragma unroll
    for (int off = 32; off >= 1; off >>= 1)
        dot += __shfl_down(dot, off, 64);

    if (lane == 0) hprime[row] = dot * dinv[row];
}

// ---------------- gather pass 1: per-(bucket,split) 32KB-LDS float accum ------
__global__ __launch_bounds__(P1T) void gather_p1_kernel(const unsigned int* __restrict__ packed,
                                                        const int* __restrict__ cursor,
                                                        const float* __restrict__ hprime,
                                                        float* __restrict__ gpart,
                                                        int NBK, int CAP) {
    int b = blockIdx.x / SPLIT;
    int part = blockIdx.x % SPLIT;
    __shared__ float acc[NPB];                 // 32 KB
    for (int i = threadIdx.x; i < NPB; i += P1T) acc[i] = 0.f;
    __syncthreads();
    int s0 = b * CAP;
    int s1 = min(cursor[b * CPAD], (b + 1) * CAP);
    int cnt = s1 - s0;
    int n4 = cnt >> 2;
    const uint4* p4 = reinterpret_cast<const uint4*>(packed + s0);
    for (int i = threadIdx.x + part * P1T; i < n4; i += SPLIT * P1T) {
        uint4 p = p4[i];
        atomicAdd(&acc[p.x & (NPB - 1)], hprime[p.x >> NPB_SHIFT]);
        atomicAdd(&acc[p.y & (NPB - 1)], hprime[p.y >> NPB_SHIFT]);
        atomicAdd(&acc[p.z & (NPB - 1)], hprime[p.z >> NPB_SHIFT]);
        atomicAdd(&acc[p.w & (NPB - 1)], hprime[p.w >> NPB_SHIFT]);
    }
    if (part == 0 && threadIdx.x < (cnt & 3)) {
        unsigned p = packed[s0 + (n4 << 2) + threadIdx.x];
        atomicAdd(&acc[p & (NPB - 1)], hprime[p >> NPB_SHIFT]);
    }
    __syncthreads();
    float* gp = gpart + (size_t)(b * SPLIT + part) * NPB;
    for (int i = threadIdx.x; i < NPB; i += P1T) gp[i] = acc[i];   // streaming
}

// ---------------- gather reduce + finalize ----------------
__global__ void gather_red_kernel(const float* __restrict__ gpart,
                                  const float* __restrict__ hprime,
                                  const float* __restrict__ dinv,
                                  const float* __restrict__ bias,
                                  float* __restrict__ out, int n) {
    int v = blockIdx.x * blockDim.x + threadIdx.x;
    if (v < n) {
        int b = v >> NPB_SHIFT;
        int idx = v & (NPB - 1);
        const float* gp = gpart + (size_t)(b * SPLIT) * NPB + idx;
        float s = 0.f;
        #pragma unroll
        for (int k = 0; k < SPLIT; ++k) s += gp[(size_t)k * NPB];
        float val = dinv[v] * (s + hprime[v]) + bias[0];
        out[v] = val > 0.f ? val : 0.f;
    }
}

// ---------------- fallback path (global atomics; tiny ws only) ----------------
__global__ void deg_atomic_kernel(const int* __restrict__ dst, int* __restrict__ deg, int e4) {
    int i = blockIdx.x * blockDim.x + threadIdx.x;
    if (i < e4) {
        int4 d = reinterpret_cast<const int4*>(dst)[i];
        atomicAdd(&deg[d.x], 1);
        atomicAdd(&deg[d.y], 1);
        atomicAdd(&deg[d.z], 1);
        atomicAdd(&deg[d.w], 1);
    }
}
__global__ void gemv_scaled_fb_kernel(const float* __restrict__ x, const float* __restrict__ W,
                                      const int* __restrict__ deg, float* __restrict__ hprime,
                                      int n) {
    int wave = threadIdx.x >> 6;
    int lane = threadIdx.x & 63;
    int row = blockIdx.x * 4 + wave;
    if (row >= n) return;
    const float4* xr = reinterpret_cast<const float4*>(x + (size_t)row * GCN_D);
    const float4* Wv = reinterpret_cast<const float4*>(W);
    float4 a0 = xr[lane], w0 = Wv[lane];
    float4 a1 = xr[lane + 64], w1 = Wv[lane + 64];
    float dot = a0.x * w0.x + a0.y * w0.y + a0.z * w0.z + a0.w * w0.w
              + a1.x * w1.x + a1.y * w1.y + a1.z * w1.z + a1.w * w1.w;
    #pragma unroll
    for (int off = 32; off >= 1; off >>= 1) dot += __shfl_down(dot, off, 64);
    if (lane == 0) hprime[row] = dot * rsqrtf((float)(deg[row] + 1));
}
__global__ void scatter_kernel(const int* __restrict__ src, const int* __restrict__ dst,
                               const float* __restrict__ hprime, float* __restrict__ acc,
                               int e4) {
    int i = blockIdx.x * blockDim.x + threadIdx.x;
    if (i < e4) {
        int4 s = reinterpret_cast<const int4*>(src)[i];
        int4 d = reinterpret_cast<const int4*>(dst)[i];
        atomicAdd(&acc[d.x], hprime[s.x]);
        atomicAdd(&acc[d.y], hprime[s.y]);
        atomicAdd(&acc[d.z], hprime[s.z]);
        atomicAdd(&acc[d.w], hprime[s.w]);
    }
}
__global__ void final_fb_kernel(const float* __restrict__ hprime, const float* __restrict__ accg,
                                const int* __restrict__ deg, const float* __restrict__ bptr,
                                float* __restrict__ out, int n) {
    int i = blockIdx.x * blockDim.x + threadIdx.x;
    if (i < n) {
        float dinv = rsqrtf((float)(deg[i] + 1));
        float v = dinv * (accg[i] + hprime[i]) + bptr[0];
        out[i] = v > 0.0f ? v : 0.0f;
    }
}

extern "C" void kernel_launch(void* const* d_in, const int* in_sizes, int n_in,
                              void* d_out, int out_size, void* d_ws, size_t ws_size,
                              hipStream_t stream) {
    const float* x    = (const float*)d_in[0];
    const int*   ei   = (const int*)d_in[1];   // [2, E]: row0 = src, row1 = dst
    const float* W    = (const float*)d_in[2];
    const float* bias = (const float*)d_in[3];
    float* out = (float*)d_out;

    const int n = in_sizes[0] / GCN_D;         // 200000
    const int E = in_sizes[1] / 2;             // 12800000
    const int e4 = E / 4;

    const int* src = ei;
    const int* dst = ei + E;

    const int NBK = (n + NPB - 1) >> NPB_SHIFT;   // 25

    // bucket capacity: ~1.125x mean load + slack (sigma ~700, huge margin)
    long long lam = ((long long)E * NPB + n - 1) / (n > 0 ? n : 1);
    if (lam < 16) lam = 16;
    long long capll = lam + lam / 8 + 4096;
    int CAP = (int)((capll + 3) & ~3LL);

    // ws layout: dinv[n] | hprime[n] | cursor | dpart[NBK*SPLIT*NPB] | gpart[same] | packed[NBK*CAP]
    auto align64 = [](size_t v) { return (v + 63) & ~(size_t)63; };
    size_t off_dinv   = 0;
    size_t off_hprime = align64(off_dinv   + (size_t)n * 4);
    size_t off_cursor = align64(off_hprime + (size_t)n * 4);
    size_t off_dpart  = align64(off_cursor + (size_t)MAXNBK * CPAD * 4);
    size_t off_gpart  = align64(off_dpart  + (size_t)NBK * SPLIT * NPB * 4);
    size_t off_packed = align64(off_gpart  + (size_t)NBK * SPLIT * NPB * 4);
    size_t needed     = off_packed + (size_t)NBK * CAP * 4;

    char* ws = (char*)d_ws;
    float* dinv   = (float*)(ws + off_dinv);
    float* hprime = (float*)(ws + off_hprime);

    if (NBK <= MAXNBK && n <= (1 << 18) && ws_size >= needed) {
        int* cursor = (int*)(ws + off_cursor);
        int* dpart  = (int*)(ws + off_dpart);
        float* gpart = (float*)(ws + off_gpart);
        unsigned int* packed = (unsigned int*)(ws + off_packed);

        init_cursor_kernel<<<1, 64, 0, stream>>>(cursor, NBK, CAP);
        place_kernel<<<(E + CHUNK - 1) / CHUNK, PT, 0, stream>>>(src, dst, cursor, packed, E, NBK, CAP);
        deg_p1_kernel<<<NBK * SPLIT, P1T, 0, stream>>>(packed, cursor, dpart, NBK, CAP);
        deg_red_kernel<<<(n + 255) / 256, 256, 0, stream>>>(dpart, dinv, n);
        gemv_kernel<<<(n + 3) / 4, 256, 0, stream>>>(x, W, dinv, hprime, n);
        gather_p1_kernel<<<NBK * SPLIT, P1T, 0, stream>>>(packed, cursor, hprime, gpart, NBK, CAP);
        gather_red_kernel<<<(n + 255) / 256, 256, 0, stream>>>(gpart, hprime, dinv, bias, out, n);
    } else {
        // fallback: atomic path (slow but correct, tiny ws)
        int*   deg   = (int*)(ws + off_dinv);
        float* accfb = (float*)(ws + off_cursor);
        hipMemsetAsync(ws, 0, off_cursor + (size_t)n * 4, stream);
        deg_atomic_kernel<<<(e4 + 255) / 256, 256, 0, stream>>>(dst, deg, e4);
        gemv_scaled_fb_kernel<<<(n + 3) / 4, 256, 0, stream>>>(x, W, deg, hprime, n);
        scatter_kernel<<<(e4 + 255) / 256, 256, 0, stream>>>(src, dst, hprime, accfb, e4);
        final_fb_kernel<<<(n + 255) / 256, 256, 0, stream>>>(hprime, accfb, deg, bias, out, n);
    }
}